// Round 9
// baseline (340.105 us; speedup 1.0000x reference)
//
#include <hip/hip_runtime.h>
#include <stdint.h>

// Problem constants (reference setup_inputs: N=4096, D=256, C=1000)
#define NR 4096
#define DD 256
#define NC_TOT 4096000
#define TILES 32
#define NTRI 528
#define NBLK_GRAM 512              // persistent blocks, 2/CU (64 KB LDS each)

typedef float f32x4 __attribute__((ext_vector_type(4)));
typedef unsigned char u8;

// ws layout:
//   [0,64)                   u32 counters: [0]=gram-done, [1]=prep-done
//   [256,  +512*4)           mse per-block partials
//   [16384, +512*4)          gram per-block partials
//   [32768, +6*4096*4)       fp32 row sq-norms (exact, from fp32 input)
//   [131072, +6*4096*256)    fp8 e4m3 features, PANEL-major, granule-major:
//     [mat(6)][panel(32)] -> 32 KB panel as [g(32)][row(128)][8B], g=col/8
#define WS_MSEP_OFF  256
#define WS_FEATP_OFF 16384
#define WS_SQN_OFF   32768
#define WS_FP8_OFF   131072

// ---------------- init: zero the counters (graph-safe tiny kernel) --------
__global__ __launch_bounds__(64) void init_kernel(unsigned* __restrict__ cnt)
{
    if (threadIdx.x < 16) cnt[threadIdx.x] = 0u;
}

// Compute one K=128 half-stage from buf[BI] into the *named* accumulator ACC
// (rule #20: compile-time names/indices only -> registers). Verbatim from the
// session-best R2/R8 kernel -> bitwise-identical accumulation.
#define COMPUTE_STAGE(BI, ACC)                                                 \
  do {                                                                         \
    const u8* tA_ = &buf[BI][0];                                               \
    const u8* tB_ = &buf[BI][16384];                                           \
    __builtin_amdgcn_s_setprio(1);                                             \
    _Pragma("unroll")                                                          \
    for (int kc = 0; kc < 4; kc++) {                                           \
      const int gg = kc * 4 + quad;                                            \
      long a_[4], b_[2];                                                       \
      _Pragma("unroll")                                                        \
      for (int mi = 0; mi < 4; mi++)                                           \
        a_[mi] = *(const long*)&tA_[gg * 1024 + (wm * 64 + mi * 16 + l16) * 8];\
      _Pragma("unroll")                                                        \
      for (int ni = 0; ni < 2; ni++)                                           \
        b_[ni] = *(const long*)&tB_[gg * 1024 + (wn * 32 + ni * 16 + l16) * 8];\
      _Pragma("unroll")                                                        \
      for (int mi = 0; mi < 4; mi++)                                           \
        _Pragma("unroll")                                                      \
        for (int ni = 0; ni < 2; ni++)                                         \
          ACC[mi][ni] = __builtin_amdgcn_mfma_f32_16x16x32_fp8_fp8(            \
              a_[mi], b_[ni], ACC[mi][ni], 0, 0, 0);                           \
    }                                                                          \
    __builtin_amdgcn_s_setprio(0);                                             \
  } while (0)

#define RESET_ACC()                                                            \
  do {                                                                         \
    _Pragma("unroll")                                                          \
    for (int a4 = 0; a4 < 4; a4++)                                             \
      _Pragma("unroll")                                                        \
      for (int b2 = 0; b2 < 2; b2++) {                                         \
        accp[a4][b2] = f32x4{0.f, 0.f, 0.f, 0.f};                              \
        acct[a4][b2] = f32x4{0.f, 0.f, 0.f, 0.f};                              \
      }                                                                        \
  } while (0)

// ------------- FUSED prep + label-MSE + fp8 Gram + pairwise-L2 ------------
// Single persistent kernel, 512 blocks (EXACTLY 2/CU x 256 CU, LDS-capacity
// limited -> all co-resident -> spin barrier is deadlock-free), 512 threads.
// Phases per block:
//   A) convert 48 rows fp32->fp8 (granule-major) + row norms
//      -> threadfence (release) -> atomicAdd(cnt[1])
//   B) label-MSE over pred/target (independent of q8: overlaps stragglers)
//   C) spin-acquire cnt[1]==512 -> fence  (Guideline-16 pattern, same
//      mechanism as the existing featp/cnt final reduction)
//   D) gram tile loop: BYTE-IDENTICAL to R8 (session-best schedule; ledger:
//      counted-vmcnt R3:47, 3-domain R4:70, no-LDS R5:68, hybrid R6:54,
//      MX R7:103-spilled all regressed -- do not revisit)
__global__ __launch_bounds__(512, 4) void gram_loss_kernel(
    const float* __restrict__ m0, const float* __restrict__ m1,
    const float* __restrict__ m2, const float* __restrict__ m3,
    const float* __restrict__ m4, const float* __restrict__ m5,
    const float4* __restrict__ pred, const float4* __restrict__ target,
    u8* __restrict__ q8, float* __restrict__ sqn,
    float* __restrict__ featp, float* __restrict__ msep,
    unsigned* __restrict__ cnt, float* __restrict__ out)
{
    __shared__ u8 buf[2][32768];       // two 32 KB (A-half | B-half) stages
    __shared__ float s_red[8], s_mse[8];
    __shared__ int s_last;

    const int xcd = blockIdx.x & 7, slot = blockIdx.x >> 3;   // slot 0..63
    const int t = threadIdx.x;
    const int w = t >> 6, lane = t & 63;
    const int wm = w >> 2, wn = w & 3;        // 2x4 waves: 64-row x 32-col
    const int quad = lane >> 4, l16 = lane & 15;
    const char* qb = (const char*)q8;

    // ---- phase A: fp8 conversion + row norms (48 rows/block, 1 row/wave) --
    {
        const int base = blockIdx.x * 48;      // 512*48 = 24576 = 6*4096 rows
        #pragma unroll
        for (int j = 0; j < 6; j++) {
            const int flat = base + j * 8 + w; // wave-uniform row id
            const int mat = flat >> 12, R = flat & 4095;
            const float* mp = m0;
            if (mat == 1) mp = m1;
            else if (mat == 2) mp = m2;
            else if (mat == 3) mp = m3;
            else if (mat == 4) mp = m4;
            else if (mat == 5) mp = m5;
            const int P = R >> 7, rr = R & 127;
            float4 v = ((const float4*)(mp + (size_t)R * DD))[lane];
            float ss = v.x * v.x + v.y * v.y + v.z * v.z + v.w * v.w;
            unsigned lo = __builtin_amdgcn_cvt_pk_fp8_f32(v.x, v.y, 0u, false);
            unsigned hi = __builtin_amdgcn_cvt_pk_fp8_f32(v.z, v.w, 0u, false);
            unsigned packed = (lo & 0xffffu) | (hi << 16);
            // granule-major: col c -> g=c/8, byte c%8; lane covers c=4l..4l+3
            size_t idx = ((size_t)(mat * 32 + P) << 15)
                         + (size_t)(lane >> 1) * 1024 + rr * 8 + (lane & 1) * 4;
            *(unsigned*)(q8 + idx) = packed;
            #pragma unroll
            for (int off = 32; off; off >>= 1) ss += __shfl_down(ss, off);
            if (lane == 0) sqn[(size_t)mat * NR + R] = ss;
        }
    }
    __threadfence();                   // release q8/sqn (per-thread)
    __syncthreads();
    if (t == 0) atomicAdd(&cnt[1], 1u);

    // ---- phase B: label-MSE (independent of q8; hides barrier wait) ------
    float mse = 0.f;
    for (int i = blockIdx.x * 512 + t; i < NC_TOT / 4; i += NBLK_GRAM * 512) {
        float4 x = pred[i], yv = target[i];
        float dx = x.x - yv.x, dy = x.y - yv.y;
        float dz = x.z - yv.z, dw = x.w - yv.w;
        mse += dx * dx + dy * dy + dz * dz + dw * dw;
    }

    // ---- phase C: device barrier (all 512 blocks co-resident) ------------
    if (t == 0) {
        while (__hip_atomic_load(&cnt[1], __ATOMIC_ACQUIRE,
                                 __HIP_MEMORY_SCOPE_AGENT) < (unsigned)NBLK_GRAM)
            __builtin_amdgcn_s_sleep(2);
    }
    __syncthreads();
    __threadfence();                   // acquire: drop stale L1/L2 lines

    // ---- phase D: gram tile loop (R8-verbatim) ---------------------------
    // tile k -> feature f, triangular pair (ti, tj). XCD-pinned; rotation
    // bijective in slot per (xcd,k) -> exact cover, spread tail.
    auto tile_of = [&](int k, int& f, int& ti, int& tj) -> bool {
        int rs = (slot + k * 21 + xcd * 9) & 63;
        int idx = rs + (k << 6), lin;
        if (xcd < 6) {
            if (idx >= 196) return false;
            f = xcd >> 1; lin = (xcd & 1) + 2 * idx;
        } else {
            if (idx >= 204) return false;
            int rr = (xcd - 6) + 2 * idx;
            f = rr / 136; lin = 392 + rr - f * 136;
        }
        int a = 0, rem = lin;
        while (rem >= TILES - a) { rem -= TILES - a; a++; }
        ti = a; tj = a + rem;
        return true;
    };

    // Stage a K=128 half-tile: A-half (16 KB) by waves 0-3, B-half by 4-7.
    auto prefetch = [&](int b, int f, int ti, int tj, int tgt, int kk) {
        const int m = f + 3 * tgt;
        const size_t bA = ((size_t)(m * 32 + ti)) << 15;
        const size_t bB = ((size_t)(m * 32 + tj)) << 15;
        const char* g = qb + ((w < 4) ? bA : bB) + kk * 16384
                        + (w & 3) * 4096 + lane * 16;
        char* l = (char*)&buf[0][0] + b * 32768
                  + ((w < 4) ? 0 : 16384) + (w & 3) * 4096;
        #pragma unroll
        for (int i = 0; i < 4; i++)
            __builtin_amdgcn_global_load_lds(
                (const __attribute__((address_space(1))) void*)(g + i * 1024),
                (__attribute__((address_space(3))) void*)(l + i * 1024), 16, 0, 0);
    };

    f32x4 accp[4][2], acct[4][2];
    RESET_ACC();

    float local = 0.f;

    int fc, tic, tjc;
    tile_of(0, fc, tic, tjc);          // every (xcd,slot) has a k=0 tile
    prefetch(0, fc, tic, tjc, 0, 0);   // P,k0 -> buf0
    __syncthreads();                   // cold drain (once)

    int k = 0;
    while (true) {
        // s0: compute P,k0 from buf0; prefetch P,k1 -> buf1
        prefetch(1, fc, tic, tjc, 0, 1);
        COMPUTE_STAGE(0, accp);
        __syncthreads();

        // s1: compute P,k1 from buf1; prefetch T,k0 -> buf0
        prefetch(0, fc, tic, tjc, 1, 0);
        COMPUTE_STAGE(1, accp);
        __syncthreads();

        // s2: compute T,k0 from buf0; prefetch T,k1 -> buf1
        prefetch(1, fc, tic, tjc, 1, 1);
        COMPUTE_STAGE(0, acct);
        __syncthreads();

        // s3: compute T,k1 from buf1; prefetch next-tile P,k0 -> buf0
        int fn, tin, tjn;
        const bool more = tile_of(k + 1, fn, tin, tjn);
        if (more) prefetch(0, fn, tin, tjn, 0, 0);
        COMPUTE_STAGE(1, acct);

        {
            // epilogue for tile (fc, tic, tjc); one-sqrt identity:
            // (dp-dt)^2 = dp2 + dt2 - 2*sqrt(dp2*dt2)
            const float* sqp = sqn + (size_t)fc * NR;
            const float* sqt = sqn + (size_t)(3 + fc) * NR;
            const bool diag = (tic == tjc);
            float tl = 0.f;
            #pragma unroll
            for (int mi = 0; mi < 4; mi++) {
                const int i0 = wm * 64 + mi * 16 + quad * 4;
                const f32x4 sip = *(const f32x4*)(sqp + tic * 128 + i0);
                const f32x4 sit = *(const f32x4*)(sqt + tic * 128 + i0);
                #pragma unroll
                for (int ni = 0; ni < 2; ni++) {
                    const int j_loc = wn * 32 + ni * 16 + l16;
                    const float spj = sqp[tjc * 128 + j_loc];
                    const float stj = sqt[tjc * 128 + j_loc];
                    const f32x4 gp = accp[mi][ni], gt = acct[mi][ni];
                    #pragma unroll
                    for (int r = 0; r < 4; r++) {
                        float dp2 = fmaxf(fmaf(-2.f, gp[r], sip[r] + spj), 0.f);
                        float dt2 = fmaxf(fmaf(-2.f, gt[r], sit[r] + stj), 0.f);
                        if (diag && (i0 + r == j_loc)) { dp2 = 0.f; dt2 = 0.f; }
                        float sq = __builtin_amdgcn_sqrtf(dp2 * dt2);
                        tl += fmaf(-2.f, sq, dp2 + dt2);
                    }
                }
            }
            local += diag ? tl : 2.f * tl;
            RESET_ACC();
        }
        __syncthreads();               // buf readers done; drains prefetch
        if (!more) break;
        k++;
        fc = fn; tic = tin; tjc = tjn;
    }

    // block reduction -> one partial each for gram-loss and mse
    #pragma unroll
    for (int off = 32; off; off >>= 1) {
        local += __shfl_down(local, off);
        mse   += __shfl_down(mse, off);
    }
    if (lane == 0) { s_red[w] = local; s_mse[w] = mse; }
    __syncthreads();
    if (t == 0) {
        float bs = 0.f, ms = 0.f;
        #pragma unroll
        for (int i = 0; i < 8; i++) { bs += s_red[i]; ms += s_mse[i]; }
        featp[blockIdx.x] = bs;
        msep[blockIdx.x]  = ms;
        __threadfence();
        unsigned old = atomicAdd(&cnt[0], 1u);
        s_last = (old == NBLK_GRAM - 1) ? 1 : 0;
    }
    __syncthreads();

    if (s_last) {                       // last block: global combine
        __threadfence();
        float s2 = 0.f, m2 = 0.f;
        for (int i = t; i < NBLK_GRAM; i += 512) {
            s2 += featp[i];
            m2 += msep[i];
        }
        #pragma unroll
        for (int off = 32; off; off >>= 1) {
            s2 += __shfl_down(s2, off);
            m2 += __shfl_down(m2, off);
        }
        __shared__ float fr[8], mr[8];
        if (lane == 0) { fr[w] = s2; mr[w] = m2; }
        __syncthreads();
        if (t == 0) {
            float fs = 0.f, ms = 0.f;
            #pragma unroll
            for (int i = 0; i < 8; i++) { fs += fr[i]; ms += mr[i]; }
            out[0] = 0.2f * (ms / (float)NC_TOT) +
                     (0.8f / 3.0f) * (fs / ((float)NR * (float)NR));
        }
    }
}

extern "C" void kernel_launch(void* const* d_in, const int* in_sizes, int n_in,
                              void* d_out, int out_size, void* d_ws, size_t ws_size,
                              hipStream_t stream) {
    unsigned* cnt  = (unsigned*)d_ws;
    float* msep    = (float*)((char*)d_ws + WS_MSEP_OFF);
    float* featp   = (float*)((char*)d_ws + WS_FEATP_OFF);
    float* sqn     = (float*)((char*)d_ws + WS_SQN_OFF);
    u8* q8         = (u8*)((char*)d_ws + WS_FP8_OFF);

    init_kernel<<<1, 64, 0, stream>>>(cnt);

    gram_loss_kernel<<<NBLK_GRAM, 512, 0, stream>>>(
        (const float*)d_in[2], (const float*)d_in[3], (const float*)d_in[4],
        (const float*)d_in[5], (const float*)d_in[6], (const float*)d_in[7],
        (const float4*)d_in[0], (const float4*)d_in[1],
        q8, sqn, featp, msep, cnt, (float*)d_out);
}

// Round 10
// 139.417 us; speedup vs baseline: 2.4395x; 2.4395x over previous
//
#include <hip/hip_runtime.h>
#include <stdint.h>

// Problem constants (reference setup_inputs: N=4096, D=256, C=1000)
#define NR 4096
#define DD 256
#define NC_TOT 4096000
#define TILES 32
#define NTRI 528
#define NBLK_GRAM 512              // persistent blocks, 2/CU (64 KB LDS each)

typedef float f32x4 __attribute__((ext_vector_type(4)));
typedef unsigned char u8;

// ws layout:
//   [0,16)                   u32 gram-completion counter (zeroed by prep)
//   [256,  +512*4)           mse per-block partials (from gram blocks)
//   [16384, +512*4)          gram per-block partials
//   [32768, +6*4096*4)       fp32 row sq-norms (exact, from fp32 input)
//   [131072, +6*4096*256)    fp8 e4m3 features, PANEL-major, granule-major:
//     [mat(6)][panel(32)] -> 32 KB panel as [g(32)][row(128)][8B], g=col/8
#define WS_MSEP_OFF  256
#define WS_FEATP_OFF 16384
#define WS_SQN_OFF   32768
#define WS_FP8_OFF   131072

// ---------------- prep-lite (fp32->fp8 granule-major + row norms) ---------
// Label-MSE lives in gram's prologue (R5/R6/R8-proven); prep reads only the
// 6 feature matrices (24 MB vs 56 MB).
// NOTE (R9 lesson): prep MUST stay a separate dispatch. Fusing it into gram
// with a device spin-barrier forces cross-XCD coherence on q8 (WRITE_SIZE
// 0.05->23 MB, FETCH 25->43 MB, gram 49->304us). The launch boundary provides
// producer->consumer ordering for free.
__global__ __launch_bounds__(256) void prep_mse_kernel(
    const float* __restrict__ m0, const float* __restrict__ m1,
    const float* __restrict__ m2, const float* __restrict__ m3,
    const float* __restrict__ m4, const float* __restrict__ m5,
    u8* __restrict__ q8, float* __restrict__ sqn, unsigned* __restrict__ cnt)
{
    const int t = threadIdx.x, w = t >> 6, lane = t & 63;
    const int y = blockIdx.y;
    if (y == 0 && blockIdx.x == 0 && t == 0) *cnt = 0u;

    const float* mp = m0;
    if (y == 1) mp = m1;
    else if (y == 2) mp = m2;
    else if (y == 3) mp = m3;
    else if (y == 4) mp = m4;
    else if (y == 5) mp = m5;
    const int R = blockIdx.x * 4 + w;            // global row 0..4095
    const int P = R >> 7, rr = R & 127;          // panel, row-in-panel
    const float4* src = (const float4*)(mp + (size_t)R * DD);
    float4 v = src[lane];                        // cols 4*lane .. 4*lane+3
    float ss = v.x * v.x + v.y * v.y + v.z * v.z + v.w * v.w;
    unsigned lo = __builtin_amdgcn_cvt_pk_fp8_f32(v.x, v.y, 0u, false);
    unsigned hi = __builtin_amdgcn_cvt_pk_fp8_f32(v.z, v.w, 0u, false);
    unsigned packed = (lo & 0xffffu) | (hi << 16);
    // granule-major: col c -> g=c/8, byte c%8. Lane covers c=4l..4l+3.
    size_t idx = ((size_t)(y * 32 + P) << 15)
                 + (size_t)(lane >> 1) * 1024 + rr * 8 + (lane & 1) * 4;
    *(unsigned*)(q8 + idx) = packed;
    #pragma unroll
    for (int off = 32; off; off >>= 1) ss += __shfl_down(ss, off);
    if (lane == 0) sqn[(size_t)y * NR + R] = ss;
}

// Compute one K=128 half-stage from buf[BI] into the *named* accumulator ACC
// (rule #20: compile-time names/indices only -> registers). Verbatim from the
// session-best R2 kernel -> bitwise-identical accumulation.
#define COMPUTE_STAGE(BI, ACC)                                                 \
  do {                                                                         \
    const u8* tA_ = &buf[BI][0];                                               \
    const u8* tB_ = &buf[BI][16384];                                           \
    __builtin_amdgcn_s_setprio(1);                                             \
    _Pragma("unroll")                                                          \
    for (int kc = 0; kc < 4; kc++) {                                           \
      const int gg = kc * 4 + quad;                                            \
      long a_[4], b_[2];                                                       \
      _Pragma("unroll")                                                        \
      for (int mi = 0; mi < 4; mi++)                                           \
        a_[mi] = *(const long*)&tA_[gg * 1024 + (wm * 64 + mi * 16 + l16) * 8];\
      _Pragma("unroll")                                                        \
      for (int ni = 0; ni < 2; ni++)                                           \
        b_[ni] = *(const long*)&tB_[gg * 1024 + (wn * 32 + ni * 16 + l16) * 8];\
      _Pragma("unroll")                                                        \
      for (int mi = 0; mi < 4; mi++)                                           \
        _Pragma("unroll")                                                      \
        for (int ni = 0; ni < 2; ni++)                                         \
          ACC[mi][ni] = __builtin_amdgcn_mfma_f32_16x16x32_fp8_fp8(            \
              a_[mi], b_[ni], ACC[mi][ni], 0, 0, 0);                           \
    }                                                                          \
    __builtin_amdgcn_s_setprio(0);                                             \
  } while (0)

#define RESET_ACC()                                                            \
  do {                                                                         \
    _Pragma("unroll")                                                          \
    for (int a4 = 0; a4 < 4; a4++)                                             \
      _Pragma("unroll")                                                        \
      for (int b2 = 0; b2 < 2; b2++) {                                         \
        accp[a4][b2] = f32x4{0.f, 0.f, 0.f, 0.f};                              \
        acct[a4][b2] = f32x4{0.f, 0.f, 0.f, 0.f};                              \
      }                                                                        \
  } while (0)

// ---------------- persistent-pipelined fp8 Gram + pairwise-L2 + MSE -------
// SESSION-BEST (R8, 139.1us total: gram ~49, prep ~7, fixed harness ~83).
// 512 blocks (2/CU), 512 threads (8 waves). Stage = K=128 half (A 16KB +
// B 16KB), double-buffered = 64 KB LDS; prefetch(next)->compute(cur)->
// __syncthreads. Ledger of refuted alternatives -- do not revisit without
// new counter evidence:
//   counted-vmcnt depth-2 (R3: 47us) | 3-domain 256-thr (R4: 70us)
//   no-LDS direct (R5: 68us)         | hybrid B-direct (R6: 54us)
//   MX-scaled 32x32x64 (R7: 103us, acc spilled to scratch)
//   single-kernel fusion + device barrier (R9: 304us, XCD coherence storm)
// Remaining gap to the ~20us pipe-sum floor is barrier-phase serialization;
// the only documented lever is the full fine-grained 8-phase interleave
// (T3/T4, m196/m218) -- high-risk to port headlessly (m152 races).
__global__ __launch_bounds__(512, 4) void gram_loss_kernel(
    const u8* __restrict__ q8, const float* __restrict__ sqn,
    const float4* __restrict__ pred, const float4* __restrict__ target,
    float* __restrict__ featp, float* __restrict__ msep,
    unsigned* __restrict__ cnt, float* __restrict__ out)
{
    __shared__ u8 buf[2][32768];       // two 32 KB (A-half | B-half) stages
    __shared__ float s_red[8], s_mse[8];
    __shared__ int s_last;

    const int xcd = blockIdx.x & 7, slot = blockIdx.x >> 3;   // slot 0..63
    const int t = threadIdx.x;
    const int w = t >> 6, lane = t & 63;
    const int wm = w >> 2, wn = w & 3;        // 2x4 waves: 64-row x 32-col
    const int quad = lane >> 4, l16 = lane & 15;
    const char* qb = (const char*)q8;

    // Fused label-MSE prologue: 32 MB of pred/target reads (L3-warm across
    // bench iterations), hidden by TLP under the tile loop (R5/R6/R8-proven).
    float mse = 0.f;
    for (int i = blockIdx.x * 512 + t; i < NC_TOT / 4; i += NBLK_GRAM * 512) {
        float4 x = pred[i], yv = target[i];
        float dx = x.x - yv.x, dy = x.y - yv.y;
        float dz = x.z - yv.z, dw = x.w - yv.w;
        mse += dx * dx + dy * dy + dz * dz + dw * dw;
    }

    // tile k -> feature f, triangular pair (ti, tj). XCD-pinned; rotation
    // bijective in slot per (xcd,k) -> exact cover, spread tail.
    auto tile_of = [&](int k, int& f, int& ti, int& tj) -> bool {
        int rs = (slot + k * 21 + xcd * 9) & 63;
        int idx = rs + (k << 6), lin;
        if (xcd < 6) {
            if (idx >= 196) return false;
            f = xcd >> 1; lin = (xcd & 1) + 2 * idx;
        } else {
            if (idx >= 204) return false;
            int rr = (xcd - 6) + 2 * idx;
            f = rr / 136; lin = 392 + rr - f * 136;
        }
        int a = 0, rem = lin;
        while (rem >= TILES - a) { rem -= TILES - a; a++; }
        ti = a; tj = a + rem;
        return true;
    };

    // Stage a K=128 half-tile: A-half (16 KB) by waves 0-3, B-half by 4-7.
    auto prefetch = [&](int b, int f, int ti, int tj, int tgt, int kk) {
        const int m = f + 3 * tgt;
        const size_t bA = ((size_t)(m * 32 + ti)) << 15;
        const size_t bB = ((size_t)(m * 32 + tj)) << 15;
        const char* g = qb + ((w < 4) ? bA : bB) + kk * 16384
                        + (w & 3) * 4096 + lane * 16;
        char* l = (char*)&buf[b][0] + ((w < 4) ? 0 : 16384) + (w & 3) * 4096;
        #pragma unroll
        for (int i = 0; i < 4; i++)
            __builtin_amdgcn_global_load_lds(
                (const __attribute__((address_space(1))) void*)(g + i * 1024),
                (__attribute__((address_space(3))) void*)(l + i * 1024), 16, 0, 0);
    };

    f32x4 accp[4][2], acct[4][2];
    RESET_ACC();

    float local = 0.f;

    int fc, tic, tjc;
    tile_of(0, fc, tic, tjc);          // every (xcd,slot) has a k=0 tile
    prefetch(0, fc, tic, tjc, 0, 0);   // P,k0 -> buf0
    __syncthreads();                   // cold drain (once)

    int k = 0;
    while (true) {
        // s0: compute P,k0 from buf0; prefetch P,k1 -> buf1
        prefetch(1, fc, tic, tjc, 0, 1);
        COMPUTE_STAGE(0, accp);
        __syncthreads();

        // s1: compute P,k1 from buf1; prefetch T,k0 -> buf0
        prefetch(0, fc, tic, tjc, 1, 0);
        COMPUTE_STAGE(1, accp);
        __syncthreads();

        // s2: compute T,k0 from buf0; prefetch T,k1 -> buf1
        prefetch(1, fc, tic, tjc, 1, 1);
        COMPUTE_STAGE(0, acct);
        __syncthreads();

        // s3: compute T,k1 from buf1; prefetch next-tile P,k0 -> buf0
        int fn, tin, tjn;
        const bool more = tile_of(k + 1, fn, tin, tjn);
        if (more) prefetch(0, fn, tin, tjn, 0, 0);
        COMPUTE_STAGE(1, acct);

        {
            // epilogue for tile (fc, tic, tjc); one-sqrt identity:
            // (dp-dt)^2 = dp2 + dt2 - 2*sqrt(dp2*dt2)
            const float* sqp = sqn + (size_t)fc * NR;
            const float* sqt = sqn + (size_t)(3 + fc) * NR;
            const bool diag = (tic == tjc);
            float tl = 0.f;
            #pragma unroll
            for (int mi = 0; mi < 4; mi++) {
                const int i0 = wm * 64 + mi * 16 + quad * 4;
                const f32x4 sip = *(const f32x4*)(sqp + tic * 128 + i0);
                const f32x4 sit = *(const f32x4*)(sqt + tic * 128 + i0);
                #pragma unroll
                for (int ni = 0; ni < 2; ni++) {
                    const int j_loc = wn * 32 + ni * 16 + l16;
                    const float spj = sqp[tjc * 128 + j_loc];
                    const float stj = sqt[tjc * 128 + j_loc];
                    const f32x4 gp = accp[mi][ni], gt = acct[mi][ni];
                    #pragma unroll
                    for (int r = 0; r < 4; r++) {
                        float dp2 = fmaxf(fmaf(-2.f, gp[r], sip[r] + spj), 0.f);
                        float dt2 = fmaxf(fmaf(-2.f, gt[r], sit[r] + stj), 0.f);
                        if (diag && (i0 + r == j_loc)) { dp2 = 0.f; dt2 = 0.f; }
                        float sq = __builtin_amdgcn_sqrtf(dp2 * dt2);
                        tl += fmaf(-2.f, sq, dp2 + dt2);
                    }
                }
            }
            local += diag ? tl : 2.f * tl;
            RESET_ACC();
        }
        __syncthreads();               // buf readers done; drains prefetch
        if (!more) break;
        k++;
        fc = fn; tic = tin; tjc = tjn;
    }

    // block reduction -> one partial each for gram-loss and mse
    #pragma unroll
    for (int off = 32; off; off >>= 1) {
        local += __shfl_down(local, off);
        mse   += __shfl_down(mse, off);
    }
    if (lane == 0) { s_red[w] = local; s_mse[w] = mse; }
    __syncthreads();
    if (t == 0) {
        float bs = 0.f, ms = 0.f;
        #pragma unroll
        for (int i = 0; i < 8; i++) { bs += s_red[i]; ms += s_mse[i]; }
        featp[blockIdx.x] = bs;
        msep[blockIdx.x]  = ms;
        __threadfence();
        unsigned old = atomicAdd(cnt, 1u);
        s_last = (old == NBLK_GRAM - 1) ? 1 : 0;
    }
    __syncthreads();

    if (s_last) {                       // last block: global combine
        __threadfence();
        float s2 = 0.f, m2 = 0.f;
        for (int i = t; i < NBLK_GRAM; i += 512) {
            s2 += featp[i];
            m2 += msep[i];
        }
        #pragma unroll
        for (int off = 32; off; off >>= 1) {
            s2 += __shfl_down(s2, off);
            m2 += __shfl_down(m2, off);
        }
        __shared__ float fr[8], mr[8];
        if (lane == 0) { fr[w] = s2; mr[w] = m2; }
        __syncthreads();
        if (t == 0) {
            float fs = 0.f, ms = 0.f;
            #pragma unroll
            for (int i = 0; i < 8; i++) { fs += fr[i]; ms += mr[i]; }
            out[0] = 0.2f * (ms / (float)NC_TOT) +
                     (0.8f / 3.0f) * (fs / ((float)NR * (float)NR));
        }
    }
}

extern "C" void kernel_launch(void* const* d_in, const int* in_sizes, int n_in,
                              void* d_out, int out_size, void* d_ws, size_t ws_size,
                              hipStream_t stream) {
    unsigned* cnt  = (unsigned*)d_ws;
    float* msep    = (float*)((char*)d_ws + WS_MSEP_OFF);
    float* featp   = (float*)((char*)d_ws + WS_FEATP_OFF);
    float* sqn     = (float*)((char*)d_ws + WS_SQN_OFF);
    u8* q8         = (u8*)((char*)d_ws + WS_FP8_OFF);

    prep_mse_kernel<<<dim3(1024, 6), 256, 0, stream>>>(
        (const float*)d_in[2], (const float*)d_in[3], (const float*)d_in[4],
        (const float*)d_in[5], (const float*)d_in[6], (const float*)d_in[7],
        q8, sqn, cnt);

    gram_loss_kernel<<<NBLK_GRAM, 512, 0, stream>>>(
        q8, sqn, (const float4*)d_in[0], (const float4*)d_in[1],
        featp, msep, cnt, (float*)d_out);
}

// Round 11
// 138.764 us; speedup vs baseline: 2.4510x; 1.0047x over previous
//
#include <hip/hip_runtime.h>
#include <stdint.h>

// Problem constants (reference setup_inputs: N=4096, D=256, C=1000)
#define NR 4096
#define DD 256
#define NC_TOT 4096000
#define TILES 32
#define NTRI 528
#define NBLK_GRAM 512              // persistent blocks, 2/CU (64 KB LDS each)

typedef float f32x4 __attribute__((ext_vector_type(4)));
typedef long  v2l  __attribute__((ext_vector_type(2)));
typedef unsigned char u8;

// ws layout:
//   [0,16)                   u32 gram-completion counter (zeroed by prep)
//   [256,  +512*4)           mse per-block partials (from gram blocks)
//   [16384, +512*4)          gram per-block partials
//   [32768, +6*4096*4)       fp32 row sq-norms (exact, from fp32 input)
//   [131072, +6*4096*256)    fp8 e4m3 features, PANEL-major, b128-fragment
//     granule layout: [mat(6)][panel(32)] -> 32 KB panel, granule g=col/8
//     (1 KB each); within granule, row R (0..127), col-lo3 = c&7:
//       byte = g*1024 + (R>>5)*256 + (R&15)*16 + ((R>>4)&1)*8 + (c&7)
//     -> fragment rows (2r,2r+1) at same l16 are 16B-contiguous, so the
//     gram's A-frags load as 2x ds_read_b128 and B-frags as 1x (was 6x b64).
#define WS_MSEP_OFF  256
#define WS_FEATP_OFF 16384
#define WS_SQN_OFF   32768
#define WS_FP8_OFF   131072

// ---------------- prep-lite (fp32->fp8 b128-fragment layout + row norms) --
// Label-MSE lives in gram's prologue (R5/R6/R8-proven); prep reads only the
// 6 feature matrices (24 MB vs 56 MB).
// NOTE (R9 lesson): prep MUST stay a separate dispatch. Fusing it into gram
// with a device spin-barrier forces cross-XCD coherence on q8 (WRITE_SIZE
// 0.05->23 MB, gram 49->304us). The launch boundary orders producer->consumer
// for free.
__global__ __launch_bounds__(256) void prep_mse_kernel(
    const float* __restrict__ m0, const float* __restrict__ m1,
    const float* __restrict__ m2, const float* __restrict__ m3,
    const float* __restrict__ m4, const float* __restrict__ m5,
    u8* __restrict__ q8, float* __restrict__ sqn, unsigned* __restrict__ cnt)
{
    const int t = threadIdx.x, w = t >> 6, lane = t & 63;
    const int y = blockIdx.y;
    if (y == 0 && blockIdx.x == 0 && t == 0) *cnt = 0u;

    const float* mp = m0;
    if (y == 1) mp = m1;
    else if (y == 2) mp = m2;
    else if (y == 3) mp = m3;
    else if (y == 4) mp = m4;
    else if (y == 5) mp = m5;
    const int R = blockIdx.x * 4 + w;            // global row 0..4095
    const int P = R >> 7, rr = R & 127;          // panel, row-in-panel
    const float4* src = (const float4*)(mp + (size_t)R * DD);
    float4 v = src[lane];                        // cols 4*lane .. 4*lane+3
    float ss = v.x * v.x + v.y * v.y + v.z * v.z + v.w * v.w;
    unsigned lo = __builtin_amdgcn_cvt_pk_fp8_f32(v.x, v.y, 0u, false);
    unsigned hi = __builtin_amdgcn_cvt_pk_fp8_f32(v.z, v.w, 0u, false);
    unsigned packed = (lo & 0xffffu) | (hi << 16);
    // b128-fragment layout: g = c>>3 = lane>>1; c&7 covers (lane&1)*4+0..3
    const int rh = rr >> 4;
    size_t idx = ((size_t)(y * 32 + P) << 15)
                 + (size_t)(lane >> 1) * 1024 + (rh >> 1) * 256
                 + (rr & 15) * 16 + (rh & 1) * 8 + (lane & 1) * 4;
    *(unsigned*)(q8 + idx) = packed;
    #pragma unroll
    for (int off = 32; off; off >>= 1) ss += __shfl_down(ss, off);
    if (lane == 0) sqn[(size_t)y * NR + R] = ss;
}

// Compute one K=128 half-stage from buf[BI] into the *named* accumulator ACC
// (rule #20: compile-time names/indices only -> registers). Fragment VALUES
// and MFMA chain order are byte-identical to R8 (only the LDS byte layout
// moved); ZC=1 replaces RESET_ACC with a literal-zero C at kc==0 (R6-proven,
// same accumulation chain). A-frags: 2x ds_read_b128; B-frags: 1x.
#define COMPUTE_STAGE(BI, ACC, ZC)                                             \
  do {                                                                         \
    const u8* tA_ = &buf[BI][0];                                               \
    const u8* tB_ = &buf[BI][16384];                                           \
    __builtin_amdgcn_s_setprio(1);                                             \
    _Pragma("unroll")                                                          \
    for (int kc = 0; kc < 4; kc++) {                                           \
      const int gg = kc * 4 + quad;                                            \
      v2l av0 = *(const v2l*)&tA_[gg * 1024 + wm * 512 + l16 * 16];            \
      v2l av1 = *(const v2l*)&tA_[gg * 1024 + wm * 512 + 256 + l16 * 16];      \
      v2l bv  = *(const v2l*)&tB_[gg * 1024 + wn * 256 + l16 * 16];            \
      long a_[4] = { av0[0], av0[1], av1[0], av1[1] };                         \
      long b_[2] = { bv[0], bv[1] };                                           \
      _Pragma("unroll")                                                        \
      for (int mi = 0; mi < 4; mi++)                                           \
        _Pragma("unroll")                                                      \
        for (int ni = 0; ni < 2; ni++) {                                       \
          if ((ZC) && kc == 0)                                                 \
            ACC[mi][ni] = __builtin_amdgcn_mfma_f32_16x16x32_fp8_fp8(          \
                a_[mi], b_[ni], f32x4{0.f, 0.f, 0.f, 0.f}, 0, 0, 0);           \
          else                                                                 \
            ACC[mi][ni] = __builtin_amdgcn_mfma_f32_16x16x32_fp8_fp8(          \
                a_[mi], b_[ni], ACC[mi][ni], 0, 0, 0);                         \
        }                                                                      \
    }                                                                          \
    __builtin_amdgcn_s_setprio(0);                                             \
  } while (0)

// ---------------- persistent-pipelined fp8 Gram + pairwise-L2 + MSE -------
// SESSION-BEST STRUCTURE (R8/R10: 139.1/139.4us total; gram ~49-53).
// 512 blocks (2/CU), 512 threads (8 waves). Stage = K=128 half (A 16KB +
// B 16KB), double-buffered = 64 KB LDS; prefetch(next)->compute(cur)->
// __syncthreads (the T3/T4 minimum 2-phase). Ledger of refuted alternatives
// -- do not revisit without new counter evidence:
//   counted-vmcnt depth-2 (R3: 47us) | 3-domain 256-thr (R4: 70us)
//   no-LDS direct (R5: 68us)         | hybrid B-direct (R6: 54us)
//   MX-scaled 32x32x64 (R7: 103us, acc spilled)
//   single-kernel fusion + device barrier (R9: 304us, XCD coherence storm)
// This round: layout-only b128 ds_read change (24->12 LDS instrs/stage-wave).
__global__ __launch_bounds__(512, 4) void gram_loss_kernel(
    const u8* __restrict__ q8, const float* __restrict__ sqn,
    const float4* __restrict__ pred, const float4* __restrict__ target,
    float* __restrict__ featp, float* __restrict__ msep,
    unsigned* __restrict__ cnt, float* __restrict__ out)
{
    __shared__ __align__(16) u8 buf[2][32768];   // two (A 16K | B 16K) stages
    __shared__ float s_red[8], s_mse[8];
    __shared__ int s_last;

    const int xcd = blockIdx.x & 7, slot = blockIdx.x >> 3;   // slot 0..63
    const int t = threadIdx.x;
    const int w = t >> 6, lane = t & 63;
    const int wm = w >> 2, wn = w & 3;        // 2x4 waves: 64-row x 32-col
    const int quad = lane >> 4, l16 = lane & 15;
    const char* qb = (const char*)q8;

    // Fused label-MSE prologue: 32 MB of pred/target reads, hidden by TLP
    // under the tile loop (R5/R6/R8-proven).
    float mse = 0.f;
    for (int i = blockIdx.x * 512 + t; i < NC_TOT / 4; i += NBLK_GRAM * 512) {
        float4 x = pred[i], yv = target[i];
        float dx = x.x - yv.x, dy = x.y - yv.y;
        float dz = x.z - yv.z, dw = x.w - yv.w;
        mse += dx * dx + dy * dy + dz * dz + dw * dw;
    }

    // tile k -> feature f, triangular pair (ti, tj). XCD-pinned; rotation
    // bijective in slot per (xcd,k) -> exact cover, spread tail.
    auto tile_of = [&](int k, int& f, int& ti, int& tj) -> bool {
        int rs = (slot + k * 21 + xcd * 9) & 63;
        int idx = rs + (k << 6), lin;
        if (xcd < 6) {
            if (idx >= 196) return false;
            f = xcd >> 1; lin = (xcd & 1) + 2 * idx;
        } else {
            if (idx >= 204) return false;
            int rr = (xcd - 6) + 2 * idx;
            f = rr / 136; lin = 392 + rr - f * 136;
        }
        int a = 0, rem = lin;
        while (rem >= TILES - a) { rem -= TILES - a; a++; }
        ti = a; tj = a + rem;
        return true;
    };

    // Stage a K=128 half-tile: A-half (16 KB) by waves 0-3, B-half by 4-7.
    // Linear granule-block copy; intra-granule layout is opaque bytes here
    // (prep wrote the b128-fragment permutation -> LDS inherits it).
    auto prefetch = [&](int b, int f, int ti, int tj, int tgt, int kk) {
        const int m = f + 3 * tgt;
        const size_t bA = ((size_t)(m * 32 + ti)) << 15;
        const size_t bB = ((size_t)(m * 32 + tj)) << 15;
        const char* g = qb + ((w < 4) ? bA : bB) + kk * 16384
                        + (w & 3) * 4096 + lane * 16;
        char* l = (char*)&buf[b][0] + ((w < 4) ? 0 : 16384) + (w & 3) * 4096;
        #pragma unroll
        for (int i = 0; i < 4; i++)
            __builtin_amdgcn_global_load_lds(
                (const __attribute__((address_space(1))) void*)(g + i * 1024),
                (__attribute__((address_space(3))) void*)(l + i * 1024), 16, 0, 0);
    };

    f32x4 accp[4][2], acct[4][2];
    float local = 0.f;

    int fc, tic, tjc;
    tile_of(0, fc, tic, tjc);          // every (xcd,slot) has a k=0 tile
    prefetch(0, fc, tic, tjc, 0, 0);   // P,k0 -> buf0
    __syncthreads();                   // cold drain (once)

    int k = 0;
    while (true) {
        // s0: compute P,k0 from buf0 (zero-C); prefetch P,k1 -> buf1
        prefetch(1, fc, tic, tjc, 0, 1);
        COMPUTE_STAGE(0, accp, 1);
        __syncthreads();

        // s1: compute P,k1 from buf1; prefetch T,k0 -> buf0
        prefetch(0, fc, tic, tjc, 1, 0);
        COMPUTE_STAGE(1, accp, 0);
        __syncthreads();

        // s2: compute T,k0 from buf0 (zero-C); prefetch T,k1 -> buf1
        prefetch(1, fc, tic, tjc, 1, 1);
        COMPUTE_STAGE(0, acct, 1);
        __syncthreads();

        // s3: compute T,k1 from buf1; prefetch next-tile P,k0 -> buf0
        int fn, tin, tjn;
        const bool more = tile_of(k + 1, fn, tin, tjn);
        if (more) prefetch(0, fn, tin, tjn, 0, 0);
        COMPUTE_STAGE(1, acct, 0);

        {
            // epilogue for tile (fc, tic, tjc); one-sqrt identity:
            // (dp-dt)^2 = dp2 + dt2 - 2*sqrt(dp2*dt2)
            const float* sqp = sqn + (size_t)fc * NR;
            const float* sqt = sqn + (size_t)(3 + fc) * NR;
            const bool diag = (tic == tjc);
            float tl = 0.f;
            #pragma unroll
            for (int mi = 0; mi < 4; mi++) {
                const int i0 = wm * 64 + mi * 16 + quad * 4;
                const f32x4 sip = *(const f32x4*)(sqp + tic * 128 + i0);
                const f32x4 sit = *(const f32x4*)(sqt + tic * 128 + i0);
                #pragma unroll
                for (int ni = 0; ni < 2; ni++) {
                    const int j_loc = wn * 32 + ni * 16 + l16;
                    const float spj = sqp[tjc * 128 + j_loc];
                    const float stj = sqt[tjc * 128 + j_loc];
                    const f32x4 gp = accp[mi][ni], gt = acct[mi][ni];
                    #pragma unroll
                    for (int r = 0; r < 4; r++) {
                        float dp2 = fmaxf(fmaf(-2.f, gp[r], sip[r] + spj), 0.f);
                        float dt2 = fmaxf(fmaf(-2.f, gt[r], sit[r] + stj), 0.f);
                        if (diag && (i0 + r == j_loc)) { dp2 = 0.f; dt2 = 0.f; }
                        float sq = __builtin_amdgcn_sqrtf(dp2 * dt2);
                        tl += fmaf(-2.f, sq, dp2 + dt2);
                    }
                }
            }
            local += diag ? tl : 2.f * tl;
        }
        __syncthreads();               // buf readers done; drains prefetch
        if (!more) break;
        k++;
        fc = fn; tic = tin; tjc = tjn;
    }

    // block reduction -> one partial each for gram-loss and mse
    #pragma unroll
    for (int off = 32; off; off >>= 1) {
        local += __shfl_down(local, off);
        mse   += __shfl_down(mse, off);
    }
    if (lane == 0) { s_red[w] = local; s_mse[w] = mse; }
    __syncthreads();
    if (t == 0) {
        float bs = 0.f, ms = 0.f;
        #pragma unroll
        for (int i = 0; i < 8; i++) { bs += s_red[i]; ms += s_mse[i]; }
        featp[blockIdx.x] = bs;
        msep[blockIdx.x]  = ms;
        __threadfence();
        unsigned old = atomicAdd(cnt, 1u);
        s_last = (old == NBLK_GRAM - 1) ? 1 : 0;
    }
    __syncthreads();

    if (s_last) {                       // last block: global combine
        __threadfence();
        float s2 = 0.f, m2 = 0.f;
        for (int i = t; i < NBLK_GRAM; i += 512) {
            s2 += featp[i];
            m2 += msep[i];
        }
        #pragma unroll
        for (int off = 32; off; off >>= 1) {
            s2 += __shfl_down(s2, off);
            m2 += __shfl_down(m2, off);
        }
        __shared__ float fr[8], mr[8];
        if (lane == 0) { fr[w] = s2; mr[w] = m2; }
        __syncthreads();
        if (t == 0) {
            float fs = 0.f, ms = 0.f;
            #pragma unroll
            for (int i = 0; i < 8; i++) { fs += fr[i]; ms += mr[i]; }
            out[0] = 0.2f * (ms / (float)NC_TOT) +
                     (0.8f / 3.0f) * (fs / ((float)NR * (float)NR));
        }
    }
}

extern "C" void kernel_launch(void* const* d_in, const int* in_sizes, int n_in,
                              void* d_out, int out_size, void* d_ws, size_t ws_size,
                              hipStream_t stream) {
    unsigned* cnt  = (unsigned*)d_ws;
    float* msep    = (float*)((char*)d_ws + WS_MSEP_OFF);
    float* featp   = (float*)((char*)d_ws + WS_FEATP_OFF);
    float* sqn     = (float*)((char*)d_ws + WS_SQN_OFF);
    u8* q8         = (u8*)((char*)d_ws + WS_FP8_OFF);

    prep_mse_kernel<<<dim3(1024, 6), 256, 0, stream>>>(
        (const float*)d_in[2], (const float*)d_in[3], (const float*)d_in[4],
        (const float*)d_in[5], (const float*)d_in[6], (const float*)d_in[7],
        q8, sqn, cnt);

    gram_loss_kernel<<<NBLK_GRAM, 512, 0, stream>>>(
        q8, sqn, (const float4*)d_in[0], (const float4*)d_in[1],
        featp, msep, cnt, (float*)d_out);
}